// Round 7
// baseline (193.537 us; speedup 1.0000x reference)
//
#include <hip/hip_runtime.h>
#include <hip/hip_bf16.h>
#include <stdint.h>

#define M_DIM 4096
#define N_DIM 4096
#define K_DIM 2048

typedef __bf16 bf16x8 __attribute__((ext_vector_type(8)));
typedef float f32x4 __attribute__((ext_vector_type(4)));
typedef unsigned short u16x8 __attribute__((ext_vector_type(8)));

// ---------------- fp32 -> bf16 (RNE) ----------------
__device__ __forceinline__ unsigned short f32_to_bf16(float f) {
  union { float f; unsigned int u; } c; c.f = f;
  unsigned int u = c.u;
  unsigned int r = (u + 0x7FFFu + ((u >> 16) & 1u)) >> 16;
  return (unsigned short)r;
}

// Convert BOTH tensors fp32->bf16 with the XOR column-granule swizzle
// (granule g of row r within each 64-col K-tile holds source granule
// g ^ (r&7)) so the forced-linear global_load_lds staging yields a
// bank-conflict-free LDS tile. Block 0 additionally zeroes S.
__global__ void __launch_bounds__(256) cvt_swz_kernel(
    const float* __restrict__ x, const float* __restrict__ w,
    unsigned short* __restrict__ xb, unsigned short* __restrict__ wb,
    float* __restrict__ S) {
  if (blockIdx.x == 0) {
#pragma unroll
    for (int k = 0; k < 16; ++k)
      S[threadIdx.x + k * 256] = 0.f;
  }

  const int nG = M_DIM * K_DIM / 8;  // granules per tensor
  int i = blockIdx.x * 256 + threadIdx.x;
  const float* src;
  unsigned short* dst;
  int gid;
  if (i < nG) { src = x; dst = xb; gid = i; }
  else        { src = w; dst = wb; gid = i - nG; }

  const int row = gid >> 8;        // K/8 = 256 granules per row
  const int cg  = gid & 255;
  const int kt  = cg >> 3;
  const int g   = cg & 7;
  const int sg  = g ^ (row & 7);   // swizzled source granule

  const float4* s4 = (const float4*)(src + (size_t)row * K_DIM + kt * 64 + sg * 8);
  float4 f0 = s4[0], f1 = s4[1];
  u16x8 o;
  o[0] = f32_to_bf16(f0.x); o[1] = f32_to_bf16(f0.y);
  o[2] = f32_to_bf16(f0.z); o[3] = f32_to_bf16(f0.w);
  o[4] = f32_to_bf16(f1.x); o[5] = f32_to_bf16(f1.y);
  o[6] = f32_to_bf16(f1.z); o[7] = f32_to_bf16(f1.w);
  ((u16x8*)dst)[gid] = o;
}

// ---------------- async global -> LDS, 16B per lane ----------------
__device__ __forceinline__ void gload_lds16(const unsigned short* g, unsigned short* l) {
  __builtin_amdgcn_global_load_lds(
      (const __attribute__((address_space(1))) unsigned int*)g,
      (__attribute__((address_space(3))) unsigned int*)l,
      16, 0, 0);
}

// ---------------- fused GEMM -> clamp -> sum exp(v-10) per row ----------------
// ONE WAVE PER BLOCK (64 threads), 128x128 tile per wave = 8x8 grid of
// 16x16x32 bf16 MFMA frags (acc = 256 regs in the unified VGPR/AGPR file).
// Why: FLOP per LDS-byte rises to 65.5 (> the 45.6 break-even of the
// 85 B/cyc ds_read pipe), and with no cross-wave barrier the 4 independent
// blocks/CU de-phase naturally - one wave's vmcnt drain overlaps the other
// three waves' MFMAs (R6's barrier phase-locked LDS and MFMA into serial
// phases: 61.6us = 29 MFMA + 30 LDS).
// XCD swizzle: same-XCD consecutive bids {x,x+8,x+16,x+24} get n-sub 0..3 of
// one 4-wide N-stripe and the SAME m-block -> A row-block + 2MB B-stripe stay
// in the per-XCD L2 (staging needs 53 B/cyc/CU vs 56 L2 ceiling).
__global__ void __launch_bounds__(64, 1) gemm_lse_kernel(
    const unsigned short* __restrict__ xb,   // [M][K] bf16, swizzled granules
    const unsigned short* __restrict__ wb,   // [N][K] bf16, swizzled granules
    const float* __restrict__ bias,          // [N]
    float* __restrict__ S) {                 // [M] partial sums of exp(clamp(v)-10)
  __shared__ __align__(16) unsigned short As[128 * 64];
  __shared__ __align__(16) unsigned short Bs[128 * 64];

  const int bid = blockIdx.x;
  const int bn0 = ((bid & 7) * 4 + ((bid >> 3) & 3)) * 128;  // XCD-local stripe
  const int bm0 = (bid >> 5) * 128;

  const int lane = threadIdx.x;
  const int lr = lane & 15;
  const int q  = lane >> 4;

  f32x4 acc[8][8];
  const f32x4 zero = {0.f, 0.f, 0.f, 0.f};
#pragma unroll
  for (int mi = 0; mi < 8; ++mi)
#pragma unroll
    for (int ni = 0; ni < 8; ++ni)
      acc[mi][ni] = zero;

  // staging: one call = 64 lanes x 16B = 1KB = 8 rows of [64 bf16]
  const int srow = lane >> 3;        // 0..7
  const int scol = (lane & 7) * 8;

  const unsigned short* xg = xb + (size_t)(bm0 + srow) * K_DIM + scol;
  const unsigned short* wg = wb + (size_t)(bn0 + srow) * K_DIM + scol;
  unsigned short* lA = As + lane * 8;   // == srow*64 + scol
  unsigned short* lB = Bs + lane * 8;

  for (int kt = 0; kt < K_DIM / 64; ++kt) {
    const int k0 = kt * 64;
#pragma unroll
    for (int c = 0; c < 16; ++c) {   // 16 calls cover 128 rows of each tile
      gload_lds16(xg + (size_t)(c * 8) * K_DIM + k0, lA + c * 8 * 64);
      gload_lds16(wg + (size_t)(c * 8) * K_DIM + k0, lB + c * 8 * 64);
    }
    __syncthreads();  // 1-wave block: compiles to the vmcnt wait, no barrier cost

#pragma unroll
    for (int ks = 0; ks < 2; ++ks) {
      // granule G = ks*4 + q; swizzled col = (G ^ (lr&7)) * 8
      const int swcol = ((ks * 4 + q) ^ (lr & 7)) * 8;
      bf16x8 af[8], bfr[8];
#pragma unroll
      for (int i = 0; i < 8; ++i) {
        af[i]  = *(const bf16x8*)(As + (i * 16 + lr) * 64 + swcol);
        bfr[i] = *(const bf16x8*)(Bs + (i * 16 + lr) * 64 + swcol);
      }
#pragma unroll
      for (int mi = 0; mi < 8; ++mi)
#pragma unroll
        for (int ni = 0; ni < 8; ++ni)
          acc[mi][ni] = __builtin_amdgcn_mfma_f32_16x16x32_bf16(
              af[mi], bfr[ni], acc[mi][ni], 0, 0, 0);
    }
    __syncthreads();  // ds_reads done before next kt's DMA overwrites the tile
  }

  // Epilogue: bias + clamp + exp(v-10); reduce across 16 lanes (128 cols);
  // one fire-and-forget atomic per row.
  float bv[8];
#pragma unroll
  for (int ni = 0; ni < 8; ++ni)
    bv[ni] = bias[bn0 + ni * 16 + lr];

#pragma unroll
  for (int mi = 0; mi < 8; ++mi) {
#pragma unroll
    for (int reg = 0; reg < 4; ++reg) {
      float s = 0.f;
#pragma unroll
      for (int ni = 0; ni < 8; ++ni) {
        float v = acc[mi][ni][reg] + bv[ni];  // SCALE_FACTOR*2 == 1.0
        v = fminf(fmaxf(v, -10.f), 10.f);
        s += __expf(v - 10.f);
      }
      s += __shfl_xor(s, 1);
      s += __shfl_xor(s, 2);
      s += __shfl_xor(s, 4);
      s += __shfl_xor(s, 8);
      if (lr == 0)
        atomicAdd(&S[bm0 + mi * 16 + q * 4 + reg], s);
    }
  }
}

// ---------------- finalize: lse = 10 + log(S); mish(lse) ----------------
__global__ void __launch_bounds__(256) finalize_kernel(const float* __restrict__ S,
                                                       float* __restrict__ out) {
  int i = blockIdx.x * blockDim.x + threadIdx.x;
  float lse = 10.0f + logf(S[i]);
  float sp = fmaxf(lse, 0.f) + log1pf(expf(-fabsf(lse)));  // stable softplus
  out[i] = lse * tanhf(sp);
}

extern "C" void kernel_launch(void* const* d_in, const int* in_sizes, int n_in,
                              void* d_out, int out_size, void* d_ws, size_t ws_size,
                              hipStream_t stream) {
  const float* x = (const float*)d_in[0];   // [4096, 2048]
  const float* W = (const float*)d_in[1];   // [4096, 2048]
  const float* b = (const float*)d_in[2];   // [4096]
  float* out = (float*)d_out;               // [4096]

  char* ws = (char*)d_ws;
  float* S = (float*)ws;                                       // 16 KB
  unsigned short* xb = (unsigned short*)(ws + 16384);          // 16 MB
  unsigned short* wb = (unsigned short*)(ws + 16384 + (size_t)M_DIM * K_DIM * 2);

  const int nG2 = 2 * M_DIM * K_DIM / 8;  // both tensors, 16B granules
  cvt_swz_kernel<<<nG2 / 256, 256, 0, stream>>>(x, W, xb, wb, S);

  gemm_lse_kernel<<<1024, 64, 0, stream>>>(xb, wb, b, S);  // 4 blocks/CU, 1 wave each

  finalize_kernel<<<M_DIM / 256, 256, 0, stream>>>(S, out);
}

// Round 8
// 154.922 us; speedup vs baseline: 1.2493x; 1.2493x over previous
//
#include <hip/hip_runtime.h>
#include <hip/hip_bf16.h>
#include <stdint.h>

#define M_DIM 4096
#define N_DIM 4096
#define K_DIM 2048

typedef __bf16 bf16x8 __attribute__((ext_vector_type(8)));
typedef float f32x4 __attribute__((ext_vector_type(4)));
typedef unsigned short u16x8 __attribute__((ext_vector_type(8)));

// ---------------- fp32 -> bf16 (RNE) ----------------
__device__ __forceinline__ unsigned short f32_to_bf16(float f) {
  union { float f; unsigned int u; } c; c.f = f;
  unsigned int u = c.u;
  unsigned int r = (u + 0x7FFFu + ((u >> 16) & 1u)) >> 16;
  return (unsigned short)r;
}

// Convert BOTH tensors fp32->bf16 with the XOR column-granule swizzle
// (granule g of row r within each 64-col K-tile holds source granule
// g ^ (r&7)) so the forced-linear global_load_lds staging yields a
// bank-conflict-free LDS tile. Block 0 additionally zeroes S.
__global__ void __launch_bounds__(256) cvt_swz_kernel(
    const float* __restrict__ x, const float* __restrict__ w,
    unsigned short* __restrict__ xb, unsigned short* __restrict__ wb,
    float* __restrict__ S) {
  if (blockIdx.x == 0) {
#pragma unroll
    for (int k = 0; k < 16; ++k)
      S[threadIdx.x + k * 256] = 0.f;
  }

  const int nG = M_DIM * K_DIM / 8;  // granules per tensor
  int i = blockIdx.x * 256 + threadIdx.x;
  const float* src;
  unsigned short* dst;
  int gid;
  if (i < nG) { src = x; dst = xb; gid = i; }
  else        { src = w; dst = wb; gid = i - nG; }

  const int row = gid >> 8;        // K/8 = 256 granules per row
  const int cg  = gid & 255;
  const int kt  = cg >> 3;
  const int g   = cg & 7;
  const int sg  = g ^ (row & 7);   // swizzled source granule

  const float4* s4 = (const float4*)(src + (size_t)row * K_DIM + kt * 64 + sg * 8);
  float4 f0 = s4[0], f1 = s4[1];
  u16x8 o;
  o[0] = f32_to_bf16(f0.x); o[1] = f32_to_bf16(f0.y);
  o[2] = f32_to_bf16(f0.z); o[3] = f32_to_bf16(f0.w);
  o[4] = f32_to_bf16(f1.x); o[5] = f32_to_bf16(f1.y);
  o[6] = f32_to_bf16(f1.z); o[7] = f32_to_bf16(f1.w);
  ((u16x8*)dst)[gid] = o;
}

// ---------------- async global -> LDS, 16B per lane ----------------
__device__ __forceinline__ void gload_lds16(const unsigned short* g, unsigned short* l) {
  __builtin_amdgcn_global_load_lds(
      (const __attribute__((address_space(1))) unsigned int*)g,
      (__attribute__((address_space(3))) unsigned int*)l,
      16, 0, 0);
}

// Stage one 256x64 A-tile + 256x64 B-tile (4 calls each; 512 lanes x 16B
// = 64 rows per call). xg/wg/lA/lB already carry the per-thread offset
// (row tid>>3, col (tid&7)*8  ->  LDS addr = base + tid*16B, the linear
// map global_load_lds requires).
__device__ __forceinline__ void stage_tile(
    const unsigned short* xg, const unsigned short* wg,
    unsigned short* lA, unsigned short* lB, int k0) {
#pragma unroll
  for (int c = 0; c < 4; ++c) {
    gload_lds16(xg + (size_t)(c * 64) * K_DIM + k0, lA + c * 64 * 64);
    gload_lds16(wg + (size_t)(c * 64) * K_DIM + k0, lB + c * 64 * 64);
  }
}

// One K=64 compute step on a staged tile pair (verified R6 inner loop).
__device__ __forceinline__ void compute_tile(
    const unsigned short* As, const unsigned short* Bs,
    int wr, int wc, int lr, int q, f32x4 acc[4][8]) {
#pragma unroll
  for (int ks = 0; ks < 2; ++ks) {
    // granule G = ks*4 + q; swizzled col = (G ^ (lr&7)) * 8
    const int swcol = ((ks * 4 + q) ^ (lr & 7)) * 8;
    bf16x8 af[4], bfr[8];
#pragma unroll
    for (int i = 0; i < 4; ++i)
      af[i]  = *(const bf16x8*)(As + (wr + i * 16 + lr) * 64 + swcol);
#pragma unroll
    for (int i = 0; i < 8; ++i)
      bfr[i] = *(const bf16x8*)(Bs + (wc + i * 16 + lr) * 64 + swcol);
#pragma unroll
    for (int mi = 0; mi < 4; ++mi)
#pragma unroll
      for (int ni = 0; ni < 8; ++ni)
        acc[mi][ni] = __builtin_amdgcn_mfma_f32_16x16x32_bf16(
            af[mi], bfr[ni], acc[mi][ni], 0, 0, 0);
  }
}

// ---------------- fused GEMM -> clamp -> sum exp(v-10) per row ----------------
// 256x256 block tile, 512 threads = 8 waves, each wave 64x128 (4x8 frags of
// 16x16x32 bf16). DOUBLE-BUFFERED LDS (128 KB dynamic), ONE barrier per
// K-tile: DMA for tile kt+1 issues right after the barrier and stays in
// flight across the whole compute(kt) phase, so the barrier's vmcnt(0)
// drain is ~free and ds_read/MFMA overlap instead of phase-locking
// (R6: 61.6us = 2304cyc LDS + 2483cyc MFMA fully SERIALIZED per kt).
__global__ void __launch_bounds__(512, 2) gemm_lse_kernel(
    const unsigned short* __restrict__ xb,   // [M][K] bf16, swizzled granules
    const unsigned short* __restrict__ wb,   // [N][K] bf16, swizzled granules
    const float* __restrict__ bias,          // [N]
    float* __restrict__ S) {                 // [M] partial sums of exp(clamp(v)-10)
  extern __shared__ __align__(16) unsigned short lds[];
  unsigned short* As0 = lds;                  // 256*64 shorts = 32 KB
  unsigned short* As1 = lds + 16384;
  unsigned short* Bs0 = lds + 32768;
  unsigned short* Bs1 = lds + 49152;

  const int tid = threadIdx.x;
  const int bm0 = blockIdx.y * 256;
  const int bn0 = blockIdx.x * 256;

  const int wave = tid >> 6, lane = tid & 63;
  const int wr = (wave & 3) * 64;    // wave row offset (0..192)
  const int wc = (wave >> 2) * 128;  // wave col offset (0/128)
  const int lr = lane & 15;
  const int q  = lane >> 4;

  f32x4 acc[4][8];
  const f32x4 zero = {0.f, 0.f, 0.f, 0.f};
#pragma unroll
  for (int mi = 0; mi < 4; ++mi)
#pragma unroll
    for (int ni = 0; ni < 8; ++ni)
      acc[mi][ni] = zero;

  const int srow = tid >> 3;        // 0..63
  const int scol = (tid & 7) * 8;

  const unsigned short* xg = xb + (size_t)(bm0 + srow) * K_DIM + scol;
  const unsigned short* wg = wb + (size_t)(bn0 + srow) * K_DIM + scol;
  unsigned short* lA = lds + tid * 8;            // into As0 (+16384 for As1)
  unsigned short* lB = lds + 32768 + tid * 8;    // into Bs0 (+16384 for Bs1)

  stage_tile(xg, wg, lA, lB, 0);                 // prologue: tile 0 -> buf0

  for (int kt = 0; kt < 32; kt += 2) {
    __syncthreads();  // drains this wave's DMA (tile kt, issued a full
                      // compute-phase ago) + syncs: buf1 free to overwrite
    if (kt + 1 < 32)
      stage_tile(xg, wg, lA + 16384, lB + 16384, (kt + 1) * 64);
    compute_tile(As0, Bs0, wr, wc, lr, q, acc);

    __syncthreads();  // drains tile kt+1 DMA; buf0 free to overwrite
    if (kt + 2 < 32)
      stage_tile(xg, wg, lA, lB, (kt + 2) * 64);
    compute_tile(As1, Bs1, wr, wc, lr, q, acc);
  }

  // Epilogue: bias + clamp + exp(v-10); reduce across 16 lanes (128 cols);
  // one fire-and-forget atomic per row per wave (32 contributions/row total).
  float bv[8];
#pragma unroll
  for (int ni = 0; ni < 8; ++ni)
    bv[ni] = bias[bn0 + wc + ni * 16 + lr];

#pragma unroll
  for (int mi = 0; mi < 4; ++mi) {
#pragma unroll
    for (int reg = 0; reg < 4; ++reg) {
      float s = 0.f;
#pragma unroll
      for (int ni = 0; ni < 8; ++ni) {
        float v = acc[mi][ni][reg] + bv[ni];  // SCALE_FACTOR*2 == 1.0
        v = fminf(fmaxf(v, -10.f), 10.f);
        s += __expf(v - 10.f);
      }
      s += __shfl_xor(s, 1);
      s += __shfl_xor(s, 2);
      s += __shfl_xor(s, 4);
      s += __shfl_xor(s, 8);
      if (lr == 0)
        atomicAdd(&S[bm0 + wr + mi * 16 + q * 4 + reg], s);
    }
  }
}

// ---------------- finalize: lse = 10 + log(S); mish(lse) ----------------
__global__ void __launch_bounds__(256) finalize_kernel(const float* __restrict__ S,
                                                       float* __restrict__ out) {
  int i = blockIdx.x * blockDim.x + threadIdx.x;
  float lse = 10.0f + logf(S[i]);
  float sp = fmaxf(lse, 0.f) + log1pf(expf(-fabsf(lse)));  // stable softplus
  out[i] = lse * tanhf(sp);
}

extern "C" void kernel_launch(void* const* d_in, const int* in_sizes, int n_in,
                              void* d_out, int out_size, void* d_ws, size_t ws_size,
                              hipStream_t stream) {
  const float* x = (const float*)d_in[0];   // [4096, 2048]
  const float* W = (const float*)d_in[1];   // [4096, 2048]
  const float* b = (const float*)d_in[2];   // [4096]
  float* out = (float*)d_out;               // [4096]

  char* ws = (char*)d_ws;
  float* S = (float*)ws;                                       // 16 KB
  unsigned short* xb = (unsigned short*)(ws + 16384);          // 16 MB
  unsigned short* wb = (unsigned short*)(ws + 16384 + (size_t)M_DIM * K_DIM * 2);

  const int nG2 = 2 * M_DIM * K_DIM / 8;  // both tensors, 16B granules
  cvt_swz_kernel<<<nG2 / 256, 256, 0, stream>>>(x, W, xb, wb, S);

  // 128 KB dynamic LDS needs the opt-in attribute (idempotent, capture-safe).
  hipFuncSetAttribute((const void*)gemm_lse_kernel,
                      hipFuncAttributeMaxDynamicSharedMemorySize, 131072);
  dim3 grid(N_DIM / 256, M_DIM / 256);  // 16 x 16 = 256 blocks, 1/CU
  gemm_lse_kernel<<<grid, 512, 131072, stream>>>(xb, wb, b, S);

  finalize_kernel<<<M_DIM / 256, 256, 0, stream>>>(S, out);
}